// Round 15
// baseline (118.957 us; speedup 1.0000x reference)
//
#include <hip/hip_runtime.h>
#include <stdint.h>

typedef unsigned short u16;
typedef short s16x8 __attribute__((ext_vector_type(8)));
typedef __bf16 bf16x8 __attribute__((ext_vector_type(8)));
typedef _Float16 f16x8 __attribute__((ext_vector_type(8)));
typedef float f32x4 __attribute__((ext_vector_type(4)));

#define SEQ    1024
#define DMODEL 1024
#define NB     4
#define NH     16
#define DH     64
#define QBLK   128
#define KVB    64
#define LOG2E  1.4426950408889634f

// ---------- scalar conversion helpers ----------
__device__ __forceinline__ u16 f2bf(float f) {
  uint32_t u = __builtin_bit_cast(uint32_t, f);
  u += 0x7fffu + ((u >> 16) & 1u);   // round-to-nearest-even
  return (u16)(u >> 16);
}
__device__ __forceinline__ u16 f2bf_rz(float f) {   // truncate (p>=0; bias cancels in P/l)
  return (u16)(__builtin_bit_cast(uint32_t, f) >> 16);
}
__device__ __forceinline__ float bf2f(u16 h) {
  uint32_t u = ((uint32_t)h) << 16;
  return __builtin_bit_cast(float, u);
}
__device__ __forceinline__ u16 f2h(float f) {       // f32 -> fp16 RNE
  return __builtin_bit_cast(u16, (_Float16)f);
}
__device__ __forceinline__ float h2f(u16 u) {
  return (float)__builtin_bit_cast(_Float16, u);
}

#define MFMA16(a, b, c)  __builtin_amdgcn_mfma_f32_16x16x32_bf16((a), (b), (c), 0, 0, 0)
#define MFMA16H(a, b, c) __builtin_amdgcn_mfma_f32_16x16x32_f16((a), (b), (c), 0, 0, 0)

template<bool F16>
__device__ __forceinline__ f32x4 MF(s16x8 a, s16x8 b, f32x4 c) {
  if constexpr (F16)
    return MFMA16H(__builtin_bit_cast(f16x8, a), __builtin_bit_cast(f16x8, b), c);
  else
    return MFMA16(__builtin_bit_cast(bf16x8, a), __builtin_bit_cast(bf16x8, b), c);
}

// ---------- async global->LDS (16B) ----------
__device__ __forceinline__ void gload_lds16(const u16* g, uintptr_t lds_addr) {
  __builtin_amdgcn_global_load_lds(
      (__attribute__((address_space(1))) void*)(uintptr_t)g,
      (__attribute__((address_space(3))) void*)lds_addr,
      16, 0, 0);
}

// ---------------- rope cos/sin table: tab[t*32+fi] = (cos, sin) ----------------
__global__ void rope_table_kernel(float2* __restrict__ tab) {
  int i = blockIdx.x * blockDim.x + threadIdx.x;   // SEQ*32
  int t = i >> 5, fi = i & 31;
  float inv = exp2f((float)fi * (-13.287712379549449f / 32.0f)); // 10000^(-fi/32)
  float ang = (float)t * inv;
  float sn, cs;
  sincosf(ang, &sn, &cs);
  tab[i] = make_float2(cs, sn);
}

// ---------------- fused cast: x,Wq,Wk,Wv -> fp16 ; Wo -> bf16 (one launch) ----------------
__global__ void cast_all_kernel(
    const float* __restrict__ x, const float* __restrict__ wq,
    const float* __restrict__ wk, const float* __restrict__ wv,
    const float* __restrict__ wo,
    u16* __restrict__ xd, u16* __restrict__ wqd, u16* __restrict__ wkd,
    u16* __restrict__ wvd, u16* __restrict__ wod)
{
  const int NX = (NB * SEQ * DMODEL) / 8;   // 524288 chunks
  const int NW = (DMODEL * DMODEL) / 8;     // 131072 chunks
  int c = blockIdx.x * blockDim.x + threadIdx.x;
  const float* src; u16* dst; bool tobf = false;
  if (c < NX)                { src = x;  dst = xd; }
  else if ((c -= NX) < NW)   { src = wq; dst = wqd; }
  else if ((c -= NW) < NW)   { src = wk; dst = wkd; }
  else if ((c -= NW) < NW)   { src = wv; dst = wvd; }
  else if ((c -= NW) < NW)   { src = wo; dst = wod; tobf = true; }
  else return;
  float f[8];
  float4 v0 = *(const float4*)(src + (size_t)c * 8);
  float4 v1 = *(const float4*)(src + (size_t)c * 8 + 4);
  f[0] = v0.x; f[1] = v0.y; f[2] = v0.z; f[3] = v0.w;
  f[4] = v1.x; f[5] = v1.y; f[6] = v1.z; f[7] = v1.w;
  union { u16 u[8]; uint4 v; } H;
#pragma unroll
  for (int e = 0; e < 8; ++e) H.u[e] = tobf ? f2bf(f[e]) : f2h(f[e]);
  *(uint4*)(dst + (size_t)c * 8) = H.v;
}

// ---------------- GEMM: C = A @ B^T, 128xBN tile, BK=64, dtype-templated ----------------
// F16=true: fp16 MFMA, mode-0 stores fp16. F16=false: bf16 MFMA.
// BN=128: QKV (4 waves 2x2, acc[4][4]).  BN=64: Wo direct-f32 (512 blocks=2/CU).
// 8-slot XOR swizzle: 0 bank conflicts (R9-measured). No XCD remap (R10 lesson).
// RoPE fusion v2 (vs R10's failed global-gather): after the final K-loop
// barrier the 32KB sA/sB LDS is dead == exactly this block's table slice
// (128 rows x 32 freqs x float2). Stage it with 8 contiguous global_load_lds
// per thread, read pairs from LDS, rotate the exact f32 acc BEFORE fp16
// quantization (one rounding step, not two). mode 1: bf16 transposed out.
struct GemmPtrs {
  const u16* B[3]; u16* C0[3]; int mode[3]; int rope[3];
};

template<bool F16, int BN>
__global__ __launch_bounds__(256) void gemm_bt_kernel(
    const u16* __restrict__ A,
    GemmPtrs P, float* __restrict__ CF, const float2* __restrict__ ropetab,
    int M, int N, int K, int out_f32)
{
  constexpr int NF = BN / 32;                   // n-frags per wave
  constexpr int BCH = BN / 32;                  // B staging chunks per thread
  __shared__ __align__(16) u16 smem[128 * 64 + BN * 64];  // sA | sB
  u16* sA = smem;
  u16* sB = smem + 128 * 64;
  const int t = threadIdx.x, lane = t & 63;
  const int wave = t >> 6;
  const int g = lane >> 4, cl = lane & 15;
  const int z = blockIdx.z;
  const u16* B = P.B[z];
  const int n0 = blockIdx.x * BN, m0 = blockIdx.y * 128;
  const int wr = wave >> 1, wc = wave & 1;

  // staging offsets for a [R][64] u16 tile: chunk c -> row c>>3, slot c&7,
  // source col pre-swizzled (rule #21), read-side applies same XOR involution
  int srow[4], scol[4], soff[4];
#pragma unroll
  for (int j = 0; j < 4; ++j) {
    int c = j * 256 + t;
    srow[j] = c >> 3;
    scol[j] = ((c & 7) ^ (srow[j] & 7)) * 8;
    soff[j] = c * 16;
  }

  f32x4 acc[4][NF] = {};

  for (int k0 = 0; k0 < K; k0 += 64) {
#pragma unroll
    for (int j = 0; j < 4; ++j)
      gload_lds16(A + (size_t)(m0 + srow[j]) * K + k0 + scol[j], (uintptr_t)sA + soff[j]);
#pragma unroll
    for (int j = 0; j < BCH; ++j)
      gload_lds16(B + (size_t)(n0 + srow[j]) * K + k0 + scol[j], (uintptr_t)sB + soff[j]);
    __syncthreads();   // drains vmcnt(0): staging landed

    s16x8 af[4][2];
#pragma unroll
    for (int m = 0; m < 4; ++m) {
      int row = wr * 64 + m * 16 + cl;
#pragma unroll
      for (int kk = 0; kk < 2; ++kk)
        af[m][kk] = *(const s16x8*)&sA[row * 64 + (((kk * 4 + g) ^ (row & 7)) * 8)];
    }
#pragma unroll
    for (int n = 0; n < NF; ++n) {
      int row = wc * (BN / 2) + n * 16 + cl;
      s16x8 b0 = *(const s16x8*)&sB[row * 64 + ((g ^ (row & 7)) * 8)];
      s16x8 b1 = *(const s16x8*)&sB[row * 64 + (((4 + g) ^ (row & 7)) * 8)];
#pragma unroll
      for (int m = 0; m < 4; ++m) {
        acc[m][n] = MF<F16>(af[m][0], b0, acc[m][n]);
        acc[m][n] = MF<F16>(af[m][1], b1, acc[m][n]);
      }
    }
    __syncthreads();
  }

  // epilogue: C/D layout col=lane&15, row=(lane>>4)*4+reg  [m89]
  if (out_f32) {
#pragma unroll
    for (int m = 0; m < 4; ++m)
#pragma unroll
      for (int n = 0; n < NF; ++n)
#pragma unroll
        for (int r = 0; r < 4; ++r) {
          int row = m0 + wr * 64 + m * 16 + g * 4 + r;
          int col = n0 + wc * (BN / 2) + n * 16 + cl;
          CF[(size_t)row * N + col] = acc[m][n][r];
        }
  } else if (P.mode[z] == 1) {
    u16* VT = P.C0[z];
#pragma unroll
    for (int m = 0; m < 4; ++m)
#pragma unroll
      for (int n = 0; n < NF; ++n) {
        int row0 = m0 + wr * 64 + m * 16 + g * 4;
        int col = n0 + wc * (BN / 2) + n * 16 + cl;
        union { u16 u[4]; uint2 v; } pk;
#pragma unroll
        for (int r = 0; r < 4; ++r) pk.u[r] = f2bf(acc[m][n][r]);
        *(uint2*)&VT[(size_t)col * M + row0] = pk.v;
      }
  } else {
    u16* C = P.C0[z];
    const bool dorope = (BN == 128) && (P.rope[z] != 0);  // block-uniform
    float2* sTab = (float2*)smem;   // aliases sA/sB (dead after final barrier)
    if (dorope) {
      // stage this block's 128x32 float2 table slice (32 KB), contiguous
      const u16* tsrc = (const u16*)(ropetab + (size_t)(m0 & (SEQ - 1)) * 32);
#pragma unroll
      for (int j = 0; j < 8; ++j) {
        int c = j * 256 + t;                 // 2048 x 16B chunks
        gload_lds16(tsrc + c * 8, (uintptr_t)sTab + c * 16);
      }
      __syncthreads();                       // drains vmcnt: table landed
    }
    const bool oddl = lane & 1;
#pragma unroll
    for (int m = 0; m < 4; ++m)
#pragma unroll
      for (int n = 0; n < NF; ++n)
#pragma unroll
        for (int r = 0; r < 4; ++r) {
          int row = m0 + wr * 64 + m * 16 + g * 4 + r;
          int col = n0 + wc * (BN / 2) + n * 16 + cl;
          float v = acc[m][n][r];
          if (dorope) {
            // pair (2p,2p+1) lives in lanes (cl, cl+1) at same row
            float2 cs = sTab[(row - m0) * 32 + ((n * 16 + cl) >> 1)];
            float pv = __shfl_xor(v, 1);
            v = oddl ? (pv * cs.y + v * cs.x)    // o' = e*sin + o*cos
                     : (v * cs.x - pv * cs.y);   // e' = e*cos - o*sin
          }
          C[(size_t)row * N + col] = F16 ? f2h(v) : f2bf(v);
        }
  }
}

// ---------------- flash attention: fp16 QK^T, bf16 PV, no-max, 2-phase ----------------
// Q,K fp16 (1-term; 8x finer mantissa than bf16). P stays bf16 (exp(s) up to
// e^50 would overflow fp16); V bf16. LDS 50 KB. (R13-validated, absmax 0.017.)
__global__ __launch_bounds__(256, 2) void attn_kernel(
    const u16* __restrict__ Q, const u16* __restrict__ K,
    const u16* __restrict__ Vt,
    u16* __restrict__ Oh)
{
  __shared__ __align__(16) u16 sK [2][KVB * 64];   // fp16 [buf][key][d]  16KB
  __shared__ __align__(16) u16 sVt[2][DH * KVB];   // bf16 [buf][d][key]  16KB
  __shared__ __align__(16) u16 sP[128 * 72];       // bf16, 18KB, wave-private rows

  const int t = threadIdx.x, lane = t & 63, wave = t >> 6;
  const int g = lane >> 4, cl = lane & 15;
  const int h = blockIdx.x & (NH - 1), b = blockIdx.x >> 4;
  const int y = blockIdx.y;
  const int qi = (y < 4) ? (7 - y) : (y - 4);  // paired work balance + heavy-first
  const int q0 = qi * QBLK;
  const size_t rowbase = (size_t)b * SEQ;
  const int colbase = h * DH;
  const int MT = NB * SEQ;

  const u16* Kb  = K + rowbase * DMODEL + colbase;
  const u16* Vtb = Vt + (size_t)(h * DH) * MT + b * SEQ;

  int srow[2], scol[2], soff[2];
#pragma unroll
  for (int j = 0; j < 2; ++j) {
    int c = j * 256 + t;
    srow[j] = c >> 3;
    scol[j] = ((c & 7) ^ (srow[j] & 7)) * 8;
    soff[j] = c * 16;
  }

  // loop-invariant LDS read offsets
  int koff0[4], koff1[4];
#pragma unroll
  for (int n = 0; n < 4; ++n) {
    int row = n * 16 + cl;
    koff0[n] = row * 64 + ((g ^ (row & 7)) * 8);
    koff1[n] = row * 64 + (((4 + g) ^ (row & 7)) * 8);
  }
  int paoff[2][2];
#pragma unroll
  for (int kk = 0; kk < 2; ++kk) {
    paoff[kk][0] = (wave * 32 + cl) * 72 + kk * 32 + g * 8;
    paoff[kk][1] = (wave * 32 + 16 + cl) * 72 + kk * 32 + g * 8;
  }

  // Q fragments fp16 (A-op: lane holds A[row=cl][k=g*8+e], second mfma k+32)
  f16x8 qf[2][2];
#pragma unroll
  for (int mf = 0; mf < 2; ++mf) {
    int qrow = q0 + wave * 32 + mf * 16 + cl;
    const u16* pq = Q + (rowbase + qrow) * DMODEL + colbase + g * 8;
    qf[mf][0] = __builtin_bit_cast(f16x8, *(const s16x8*)pq);
    qf[mf][1] = __builtin_bit_cast(f16x8, *(const s16x8*)(pq + 32));
  }

  bf16x8 ones;
#pragma unroll
  for (int e = 0; e < 8; ++e) ones[e] = (__bf16)1.0f;

  f32x4 o_acc[2][4] = {};
  f32x4 o_l[2] = {};

  const int last = 2 * qi + 1;
  const int wrow0 = q0 + wave * 32;
  const int prow0 = wave * 32;

  // prologue: stage tile 0 into buffer 0
#pragma unroll
  for (int j = 0; j < 2; ++j) {
    gload_lds16(Kb + (size_t)srow[j] * DMODEL + scol[j],  (uintptr_t)&sK[0][0] + soff[j]);
    gload_lds16(Vtb + (size_t)srow[j] * MT + scol[j],     (uintptr_t)&sVt[0][0] + soff[j]);
  }
  __syncthreads();

  int cur = 0;
  for (int kt = 0; kt <= last; ++kt) {
    const int kv0 = kt * KVB;
    // issue next tile's staging FIRST (hidden under this tile's compute)
    if (kt < last) {
      const int nk = kv0 + KVB;
#pragma unroll
      for (int j = 0; j < 2; ++j) {
        gload_lds16(Kb + (size_t)(nk + srow[j]) * DMODEL + scol[j],
                    (uintptr_t)&sK[cur ^ 1][0] + soff[j]);
        gload_lds16(Vtb + (size_t)srow[j] * MT + nk + scol[j],
                    (uintptr_t)&sVt[cur ^ 1][0] + soff[j]);
      }
    }

    const bool skip = (wrow0 + 31) < kv0;   // wave fully masked (diag tiles)
    if (!skip) {
      const bool needmask = (kv0 + 63) > wrow0;

      // QK^T: fp16 single-term
      f32x4 s[2][4];
      __builtin_amdgcn_s_setprio(1);
#pragma unroll
      for (int n = 0; n < 4; ++n) {
        f16x8 k0 = __builtin_bit_cast(f16x8, *(const s16x8*)&sK[cur][koff0[n]]);
        f16x8 k1 = __builtin_bit_cast(f16x8, *(const s16x8*)&sK[cur][koff1[n]]);
#pragma unroll
        for (int mf = 0; mf < 2; ++mf) {
          f32x4 zz = {};
          zz = MFMA16H(qf[mf][0], k0, zz);
          zz = MFMA16H(qf[mf][1], k1, zz);
          s[mf][n] = zz;
        }
      }
      __builtin_amdgcn_s_setprio(0);

      // no-max softmax: p = exp2(s*log2e), zeroed past the diagonal
#pragma unroll
      for (int mf = 0; mf < 2; ++mf) {
#pragma unroll
        for (int r = 0; r < 4; ++r) {
          int qg = wrow0 + mf * 16 + g * 4 + r;
          int prow = prow0 + mf * 16 + g * 4 + r;
#pragma unroll
          for (int n = 0; n < 4; ++n) {
            float p = exp2f(s[mf][n][r] * LOG2E);
            if (needmask && (kv0 + n * 16 + cl > qg)) p = 0.0f;
            sP[prow * 72 + n * 16 + cl] = f2bf_rz(p);
          }
        }
      }

      // PV: O += P(32x64)*Vt ; l += P*1 (bf16 MFMA)
      __builtin_amdgcn_s_setprio(1);
#pragma unroll
      for (int kk = 0; kk < 2; ++kk) {
        bf16x8 pa0 = *(const bf16x8*)&sP[paoff[kk][0]];
        bf16x8 pa1 = *(const bf16x8*)&sP[paoff[kk][1]];
#pragma unroll
        for (int n = 0; n < 4; ++n) {
          bf16x8 vf = *(const bf16x8*)&sVt[cur][(kk == 0) ? koff0[n] : koff1[n]];
          o_acc[0][n] = MFMA16(pa0, vf, o_acc[0][n]);
          o_acc[1][n] = MFMA16(pa1, vf, o_acc[1][n]);
        }
        o_l[0] = MFMA16(pa0, ones, o_l[0]);
        o_l[1] = MFMA16(pa1, ones, o_l[1]);
      }
      __builtin_amdgcn_s_setprio(0);
    }

    __syncthreads();   // drains vmcnt(0): prefetch landed; frees buf cur
    cur ^= 1;
  }

  // epilogue: normalize by l, store bf16 (feeds bf16 Wo GEMM)
#pragma unroll
  for (int mf = 0; mf < 2; ++mf)
#pragma unroll
    for (int n = 0; n < 4; ++n)
#pragma unroll
      for (int r = 0; r < 4; ++r) {
        float ov = o_acc[mf][n][r] / o_l[mf][r];
        int qrow = q0 + wave * 32 + mf * 16 + g * 4 + r;
        size_t idx = (rowbase + qrow) * DMODEL + colbase + n * 16 + cl;
        Oh[idx] = f2bf(ov);
      }
}

extern "C" void kernel_launch(void* const* d_in, const int* in_sizes, int n_in,
                              void* d_out, int out_size, void* d_ws, size_t ws_size,
                              hipStream_t stream) {
  const float* x  = (const float*)d_in[0];
  const float* Wq = (const float*)d_in[1];
  const float* Wk = (const float*)d_in[2];
  const float* Wv = (const float*)d_in[3];
  const float* Wo = (const float*)d_in[4];
  float* out = (float*)d_out;

  const int M = NB * SEQ;      // 4096
  const int D = DMODEL;        // 1024
  char* ws = (char*)d_ws;
  const size_t MB = 1u << 20;
  u16* xh16 = (u16*)(ws + 0 * MB);    // 8 MB fp16
  u16* qh16 = (u16*)(ws + 8 * MB);    // 8 MB fp16 (rope applied in GEMM epilogue)
  u16* kh16 = (u16*)(ws + 16 * MB);   // 8 MB fp16
  u16* vt   = (u16*)(ws + 24 * MB);   // 8 MB bf16, transposed [1024][4096]
  u16* oh   = (u16*)(ws + 40 * MB);   // 8 MB bf16
  u16* wq16 = (u16*)(ws + 48 * MB);   // 2 MB each
  u16* wk16 = (u16*)(ws + 50 * MB);
  u16* wv16 = (u16*)(ws + 52 * MB);
  u16* wob  = (u16*)(ws + 54 * MB);
  float2* ropetab = (float2*)(ws + 56 * MB);   // 256 KB

  // rope table + one fused cast launch: x,Wq,Wk,Wv -> fp16 ; Wo -> bf16
  rope_table_kernel<<<SEQ * 32 / 256, 256, 0, stream>>>(ropetab);
  {
    int total = M * D / 8 + 4 * (D * D / 8);
    cast_all_kernel<<<(total + 255) / 256, 256, 0, stream>>>(
        x, Wq, Wk, Wv, Wo, xh16, wq16, wk16, wv16, wob);
  }

  // fused QKV projections, fp16 1-term: Q,K fp16 out + fused RoPE (LDS table);
  // V bf16 transposed out
  {
    GemmPtrs P;
    P.B[0] = wq16; P.B[1] = wk16; P.B[2] = wv16;
    P.C0[0] = qh16; P.C0[1] = kh16; P.C0[2] = vt;
    P.mode[0] = 0; P.mode[1] = 0; P.mode[2] = 1;
    P.rope[0] = 1; P.rope[1] = 1; P.rope[2] = 0;
    gemm_bt_kernel<true, 128><<<dim3(D / 128, M / 128, 3), 256, 0, stream>>>(
        xh16, P, nullptr, ropetab, M, D, D, 0);
  }

  // causal flash attention: 512 blocks of 4 waves, pair-balanced heavy-first
  attn_kernel<<<dim3(NH * NB, 8), 256, 0, stream>>>(qh16, kh16, vt, oh);

  // output projection: bf16, 128x64 tile, 512 blocks (2/CU), direct f32 out
  {
    GemmPtrs P;
    P.B[0] = wob; P.B[1] = wob; P.B[2] = wob;
    P.C0[0] = nullptr; P.C0[1] = nullptr; P.C0[2] = nullptr;
    P.mode[0] = 0; P.mode[1] = 0; P.mode[2] = 0;
    P.rope[0] = 0; P.rope[1] = 0; P.rope[2] = 0;
    gemm_bt_kernel<false, 64><<<dim3(D / 64, M / 128, 1), 256, 0, stream>>>(
        oh, P, out, nullptr, M, D, D, 1);
  }
}

// Round 16
// 108.235 us; speedup vs baseline: 1.0991x; 1.0991x over previous
//
#include <hip/hip_runtime.h>
#include <stdint.h>

typedef unsigned short u16;
typedef short s16x8 __attribute__((ext_vector_type(8)));
typedef __bf16 bf16x8 __attribute__((ext_vector_type(8)));
typedef _Float16 f16x8 __attribute__((ext_vector_type(8)));
typedef float f32x4 __attribute__((ext_vector_type(4)));

#define SEQ    1024
#define DMODEL 1024
#define NB     4
#define NH     16
#define DH     64
#define QBLK   128
#define KVB    64
#define LOG2E  1.4426950408889634f

// ---------- scalar conversion helpers ----------
__device__ __forceinline__ u16 f2bf(float f) {
  uint32_t u = __builtin_bit_cast(uint32_t, f);
  u += 0x7fffu + ((u >> 16) & 1u);   // round-to-nearest-even
  return (u16)(u >> 16);
}
__device__ __forceinline__ u16 f2bf_rz(float f) {   // truncate (p>=0; bias cancels in P/l)
  return (u16)(__builtin_bit_cast(uint32_t, f) >> 16);
}
__device__ __forceinline__ float bf2f(u16 h) {
  uint32_t u = ((uint32_t)h) << 16;
  return __builtin_bit_cast(float, u);
}
__device__ __forceinline__ u16 f2h(float f) {       // f32 -> fp16 RNE
  return __builtin_bit_cast(u16, (_Float16)f);
}
__device__ __forceinline__ float h2f(u16 u) {
  return (float)__builtin_bit_cast(_Float16, u);
}

#define MFMA16(a, b, c)  __builtin_amdgcn_mfma_f32_16x16x32_bf16((a), (b), (c), 0, 0, 0)
#define MFMA16H(a, b, c) __builtin_amdgcn_mfma_f32_16x16x32_f16((a), (b), (c), 0, 0, 0)

template<bool F16>
__device__ __forceinline__ f32x4 MF(s16x8 a, s16x8 b, f32x4 c) {
  if constexpr (F16)
    return MFMA16H(__builtin_bit_cast(f16x8, a), __builtin_bit_cast(f16x8, b), c);
  else
    return MFMA16(__builtin_bit_cast(bf16x8, a), __builtin_bit_cast(bf16x8, b), c);
}

// ---------- async global->LDS (16B) ----------
__device__ __forceinline__ void gload_lds16(const u16* g, uintptr_t lds_addr) {
  __builtin_amdgcn_global_load_lds(
      (__attribute__((address_space(1))) void*)(uintptr_t)g,
      (__attribute__((address_space(3))) void*)lds_addr,
      16, 0, 0);
}

// ---------------- fused cast: x,Wq,Wk,Wv -> fp16 ; Wo -> bf16 (one launch) ----------------
__global__ void cast_all_kernel(
    const float* __restrict__ x, const float* __restrict__ wq,
    const float* __restrict__ wk, const float* __restrict__ wv,
    const float* __restrict__ wo,
    u16* __restrict__ xd, u16* __restrict__ wqd, u16* __restrict__ wkd,
    u16* __restrict__ wvd, u16* __restrict__ wod)
{
  const int NX = (NB * SEQ * DMODEL) / 8;   // 524288 chunks
  const int NW = (DMODEL * DMODEL) / 8;     // 131072 chunks
  int c = blockIdx.x * blockDim.x + threadIdx.x;
  const float* src; u16* dst; bool tobf = false;
  if (c < NX)                { src = x;  dst = xd; }
  else if ((c -= NX) < NW)   { src = wq; dst = wqd; }
  else if ((c -= NW) < NW)   { src = wk; dst = wkd; }
  else if ((c -= NW) < NW)   { src = wv; dst = wvd; }
  else if ((c -= NW) < NW)   { src = wo; dst = wod; tobf = true; }
  else return;
  float f[8];
  float4 v0 = *(const float4*)(src + (size_t)c * 8);
  float4 v1 = *(const float4*)(src + (size_t)c * 8 + 4);
  f[0] = v0.x; f[1] = v0.y; f[2] = v0.z; f[3] = v0.w;
  f[4] = v1.x; f[5] = v1.y; f[6] = v1.z; f[7] = v1.w;
  union { u16 u[8]; uint4 v; } H;
#pragma unroll
  for (int e = 0; e < 8; ++e) H.u[e] = tobf ? f2bf(f[e]) : f2h(f[e]);
  *(uint4*)(dst + (size_t)c * 8) = H.v;
}

// ---------------- RoPE on fp16 Q,K (in place; standalone — epilogue fusion
// regressed twice (R10 +30us, R15 +19us), do not re-attempt) ----------------
__global__ void rope_kernel(u16* __restrict__ Q, u16* __restrict__ K) {
  const int nP = (NB * SEQ) * (DMODEL / 2);
  int idx = blockIdx.x * blockDim.x + threadIdx.x;
  u16* buf; int p;
  if (idx < nP) { buf = Q; p = idx; }
  else          { buf = K; p = idx - nP; }
  int row = p >> 9;           // 512 pairs per row
  int pi  = p & 511;
  int t   = row & (SEQ - 1);
  int fi  = pi & 31;
  float inv = exp2f((float)fi * (-13.287712379549449f / 32.0f)); // 10000^(-fi/32)
  float ang = (float)t * inv;
  float sn, cs;
  sincosf(ang, &sn, &cs);
  size_t off = (size_t)row * DMODEL + pi * 2;
  uint32_t v = *(uint32_t*)(buf + off);
  float e = h2f((u16)(v & 0xffffu));
  float o = h2f((u16)(v >> 16));
  float re = e * cs - o * sn;
  float ro = e * sn + o * cs;
  *(uint32_t*)(buf + off) = (uint32_t)f2h(re) | ((uint32_t)f2h(ro) << 16);
}

// ---------------- GEMM: C = A @ B^T, 128xBN tile, BK=64, DOUBLE-BUFFERED ----------------
// R15 diagnosis: fp16 halved compute per staged byte -> the old stage->drain->
// compute loop exposed full staging latency every K-step (MfmaUtil ~20%).
// Fix = the attn kernel's proven 2-phase structure: prefetch K-step k+1 into
// buf^1 BEFORE computing k; single __syncthreads per iter drains the prefetch
// AFTER compute. LDS 64 KB (BN=128) -> 2 blocks/CU (attn runs fine at 50 KB).
// F16=true: fp16 MFMA, mode-0 stores fp16. F16=false: bf16 MFMA.
// 8-slot XOR swizzle: 0 bank conflicts (R9). No XCD remap (R10), no rope fusion.
// mode 1: bf16 transposed out (Vt[col][row]). out_f32: direct f32 store.
struct GemmPtrs {
  const u16* B[3]; u16* C0[3]; int mode[3];
};

template<bool F16, int BN>
__global__ __launch_bounds__(256) void gemm_bt_kernel(
    const u16* __restrict__ A,
    GemmPtrs P, float* __restrict__ CF,
    int M, int N, int K, int out_f32)
{
  constexpr int NF = BN / 32;                   // n-frags per wave
  constexpr int BCH = BN / 32;                  // B staging chunks per thread
  __shared__ __align__(16) u16 sA[2][128 * 64];  // 2 x 16 KB
  __shared__ __align__(16) u16 sB[2][BN * 64];   // 2 x 16|8 KB
  const int t = threadIdx.x, lane = t & 63;
  const int wave = t >> 6;
  const int g = lane >> 4, cl = lane & 15;
  const int z = blockIdx.z;
  const u16* B = P.B[z];
  const int n0 = blockIdx.x * BN, m0 = blockIdx.y * 128;
  const int wr = wave >> 1, wc = wave & 1;

  // staging offsets for a [R][64] u16 tile: chunk c -> row c>>3, slot c&7,
  // source col pre-swizzled (rule #21), read-side applies same XOR involution
  int srow[4], scol[4], soff[4];
#pragma unroll
  for (int j = 0; j < 4; ++j) {
    int c = j * 256 + t;
    srow[j] = c >> 3;
    scol[j] = ((c & 7) ^ (srow[j] & 7)) * 8;
    soff[j] = c * 16;
  }

  f32x4 acc[4][NF] = {};

  // prologue: stage k0=0 into buffer 0
#pragma unroll
  for (int j = 0; j < 4; ++j)
    gload_lds16(A + (size_t)(m0 + srow[j]) * K + scol[j], (uintptr_t)&sA[0][0] + soff[j]);
#pragma unroll
  for (int j = 0; j < BCH; ++j)
    gload_lds16(B + (size_t)(n0 + srow[j]) * K + scol[j], (uintptr_t)&sB[0][0] + soff[j]);
  __syncthreads();

  int cur = 0;
  for (int k0 = 0; k0 < K; k0 += 64) {
    // issue next K-step's staging FIRST (hidden under this step's compute)
    if (k0 + 64 < K) {
      const int nk = k0 + 64;
#pragma unroll
      for (int j = 0; j < 4; ++j)
        gload_lds16(A + (size_t)(m0 + srow[j]) * K + nk + scol[j],
                    (uintptr_t)&sA[cur ^ 1][0] + soff[j]);
#pragma unroll
      for (int j = 0; j < BCH; ++j)
        gload_lds16(B + (size_t)(n0 + srow[j]) * K + nk + scol[j],
                    (uintptr_t)&sB[cur ^ 1][0] + soff[j]);
    }

    s16x8 af[4][2];
#pragma unroll
    for (int m = 0; m < 4; ++m) {
      int row = wr * 64 + m * 16 + cl;
#pragma unroll
      for (int kk = 0; kk < 2; ++kk)
        af[m][kk] = *(const s16x8*)&sA[cur][row * 64 + (((kk * 4 + g) ^ (row & 7)) * 8)];
    }
#pragma unroll
    for (int n = 0; n < NF; ++n) {
      int row = wc * (BN / 2) + n * 16 + cl;
      s16x8 b0 = *(const s16x8*)&sB[cur][row * 64 + ((g ^ (row & 7)) * 8)];
      s16x8 b1 = *(const s16x8*)&sB[cur][row * 64 + (((4 + g) ^ (row & 7)) * 8)];
#pragma unroll
      for (int m = 0; m < 4; ++m) {
        acc[m][n] = MF<F16>(af[m][0], b0, acc[m][n]);
        acc[m][n] = MF<F16>(af[m][1], b1, acc[m][n]);
      }
    }
    __syncthreads();   // drains prefetch vmcnt + all waves done reading buf cur
    cur ^= 1;
  }

  // epilogue: C/D layout col=lane&15, row=(lane>>4)*4+reg  [m89]
  if (out_f32) {
#pragma unroll
    for (int m = 0; m < 4; ++m)
#pragma unroll
      for (int n = 0; n < NF; ++n)
#pragma unroll
        for (int r = 0; r < 4; ++r) {
          int row = m0 + wr * 64 + m * 16 + g * 4 + r;
          int col = n0 + wc * (BN / 2) + n * 16 + cl;
          CF[(size_t)row * N + col] = acc[m][n][r];
        }
  } else if (P.mode[z] == 1) {
    u16* VT = P.C0[z];
#pragma unroll
    for (int m = 0; m < 4; ++m)
#pragma unroll
      for (int n = 0; n < NF; ++n) {
        int row0 = m0 + wr * 64 + m * 16 + g * 4;
        int col = n0 + wc * (BN / 2) + n * 16 + cl;
        union { u16 u[4]; uint2 v; } pk;
#pragma unroll
        for (int r = 0; r < 4; ++r) pk.u[r] = f2bf(acc[m][n][r]);
        *(uint2*)&VT[(size_t)col * M + row0] = pk.v;
      }
  } else {
    u16* C = P.C0[z];
#pragma unroll
    for (int m = 0; m < 4; ++m)
#pragma unroll
      for (int n = 0; n < NF; ++n)
#pragma unroll
        for (int r = 0; r < 4; ++r) {
          int row = m0 + wr * 64 + m * 16 + g * 4 + r;
          int col = n0 + wc * (BN / 2) + n * 16 + cl;
          float v = acc[m][n][r];
          C[(size_t)row * N + col] = F16 ? f2h(v) : f2bf(v);
        }
  }
}

// ---------------- flash attention: fp16 QK^T, bf16 PV, no-max, 2-phase ----------------
// Q,K fp16 (1-term; 8x finer mantissa than bf16). P stays bf16 (exp(s) up to
// e^50 would overflow fp16); V bf16. LDS 50 KB. (R13-validated, absmax 0.017.)
__global__ __launch_bounds__(256, 2) void attn_kernel(
    const u16* __restrict__ Q, const u16* __restrict__ K,
    const u16* __restrict__ Vt,
    u16* __restrict__ Oh)
{
  __shared__ __align__(16) u16 sK [2][KVB * 64];   // fp16 [buf][key][d]  16KB
  __shared__ __align__(16) u16 sVt[2][DH * KVB];   // bf16 [buf][d][key]  16KB
  __shared__ __align__(16) u16 sP[128 * 72];       // bf16, 18KB, wave-private rows

  const int t = threadIdx.x, lane = t & 63, wave = t >> 6;
  const int g = lane >> 4, cl = lane & 15;
  const int h = blockIdx.x & (NH - 1), b = blockIdx.x >> 4;
  const int y = blockIdx.y;
  const int qi = (y < 4) ? (7 - y) : (y - 4);  // paired work balance + heavy-first
  const int q0 = qi * QBLK;
  const size_t rowbase = (size_t)b * SEQ;
  const int colbase = h * DH;
  const int MT = NB * SEQ;

  const u16* Kb  = K + rowbase * DMODEL + colbase;
  const u16* Vtb = Vt + (size_t)(h * DH) * MT + b * SEQ;

  int srow[2], scol[2], soff[2];
#pragma unroll
  for (int j = 0; j < 2; ++j) {
    int c = j * 256 + t;
    srow[j] = c >> 3;
    scol[j] = ((c & 7) ^ (srow[j] & 7)) * 8;
    soff[j] = c * 16;
  }

  // loop-invariant LDS read offsets
  int koff0[4], koff1[4];
#pragma unroll
  for (int n = 0; n < 4; ++n) {
    int row = n * 16 + cl;
    koff0[n] = row * 64 + ((g ^ (row & 7)) * 8);
    koff1[n] = row * 64 + (((4 + g) ^ (row & 7)) * 8);
  }
  int paoff[2][2];
#pragma unroll
  for (int kk = 0; kk < 2; ++kk) {
    paoff[kk][0] = (wave * 32 + cl) * 72 + kk * 32 + g * 8;
    paoff[kk][1] = (wave * 32 + 16 + cl) * 72 + kk * 32 + g * 8;
  }

  // Q fragments fp16 (A-op: lane holds A[row=cl][k=g*8+e], second mfma k+32)
  f16x8 qf[2][2];
#pragma unroll
  for (int mf = 0; mf < 2; ++mf) {
    int qrow = q0 + wave * 32 + mf * 16 + cl;
    const u16* pq = Q + (rowbase + qrow) * DMODEL + colbase + g * 8;
    qf[mf][0] = __builtin_bit_cast(f16x8, *(const s16x8*)pq);
    qf[mf][1] = __builtin_bit_cast(f16x8, *(const s16x8*)(pq + 32));
  }

  bf16x8 ones;
#pragma unroll
  for (int e = 0; e < 8; ++e) ones[e] = (__bf16)1.0f;

  f32x4 o_acc[2][4] = {};
  f32x4 o_l[2] = {};

  const int last = 2 * qi + 1;
  const int wrow0 = q0 + wave * 32;
  const int prow0 = wave * 32;

  // prologue: stage tile 0 into buffer 0
#pragma unroll
  for (int j = 0; j < 2; ++j) {
    gload_lds16(Kb + (size_t)srow[j] * DMODEL + scol[j],  (uintptr_t)&sK[0][0] + soff[j]);
    gload_lds16(Vtb + (size_t)srow[j] * MT + scol[j],     (uintptr_t)&sVt[0][0] + soff[j]);
  }
  __syncthreads();

  int cur = 0;
  for (int kt = 0; kt <= last; ++kt) {
    const int kv0 = kt * KVB;
    // issue next tile's staging FIRST (hidden under this tile's compute)
    if (kt < last) {
      const int nk = kv0 + KVB;
#pragma unroll
      for (int j = 0; j < 2; ++j) {
        gload_lds16(Kb + (size_t)(nk + srow[j]) * DMODEL + scol[j],
                    (uintptr_t)&sK[cur ^ 1][0] + soff[j]);
        gload_lds16(Vtb + (size_t)srow[j] * MT + nk + scol[j],
                    (uintptr_t)&sVt[cur ^ 1][0] + soff[j]);
      }
    }

    const bool skip = (wrow0 + 31) < kv0;   // wave fully masked (diag tiles)
    if (!skip) {
      const bool needmask = (kv0 + 63) > wrow0;

      // QK^T: fp16 single-term
      f32x4 s[2][4];
      __builtin_amdgcn_s_setprio(1);
#pragma unroll
      for (int n = 0; n < 4; ++n) {
        f16x8 k0 = __builtin_bit_cast(f16x8, *(const s16x8*)&sK[cur][koff0[n]]);
        f16x8 k1 = __builtin_bit_cast(f16x8, *(const s16x8*)&sK[cur][koff1[n]]);
#pragma unroll
        for (int mf = 0; mf < 2; ++mf) {
          f32x4 zz = {};
          zz = MFMA16H(qf[mf][0], k0, zz);
          zz = MFMA16H(qf[mf][1], k1, zz);
          s[mf][n] = zz;
        }
      }
      __builtin_amdgcn_s_setprio(0);

      // no-max softmax: p = exp2(s*log2e), zeroed past the diagonal
#pragma unroll
      for (int mf = 0; mf < 2; ++mf) {
#pragma unroll
        for (int r = 0; r < 4; ++r) {
          int qg = wrow0 + mf * 16 + g * 4 + r;
          int prow = prow0 + mf * 16 + g * 4 + r;
#pragma unroll
          for (int n = 0; n < 4; ++n) {
            float p = exp2f(s[mf][n][r] * LOG2E);
            if (needmask && (kv0 + n * 16 + cl > qg)) p = 0.0f;
            sP[prow * 72 + n * 16 + cl] = f2bf_rz(p);
          }
        }
      }

      // PV: O += P(32x64)*Vt ; l += P*1 (bf16 MFMA)
      __builtin_amdgcn_s_setprio(1);
#pragma unroll
      for (int kk = 0; kk < 2; ++kk) {
        bf16x8 pa0 = *(const bf16x8*)&sP[paoff[kk][0]];
        bf16x8 pa1 = *(const bf16x8*)&sP[paoff[kk][1]];
#pragma unroll
        for (int n = 0; n < 4; ++n) {
          bf16x8 vf = *(const bf16x8*)&sVt[cur][(kk == 0) ? koff0[n] : koff1[n]];
          o_acc[0][n] = MFMA16(pa0, vf, o_acc[0][n]);
          o_acc[1][n] = MFMA16(pa1, vf, o_acc[1][n]);
        }
        o_l[0] = MFMA16(pa0, ones, o_l[0]);
        o_l[1] = MFMA16(pa1, ones, o_l[1]);
      }
      __builtin_amdgcn_s_setprio(0);
    }

    __syncthreads();   // drains vmcnt(0): prefetch landed; frees buf cur
    cur ^= 1;
  }

  // epilogue: normalize by l, store bf16 (feeds bf16 Wo GEMM)
#pragma unroll
  for (int mf = 0; mf < 2; ++mf)
#pragma unroll
    for (int n = 0; n < 4; ++n)
#pragma unroll
      for (int r = 0; r < 4; ++r) {
        float ov = o_acc[mf][n][r] / o_l[mf][r];
        int qrow = q0 + wave * 32 + mf * 16 + g * 4 + r;
        size_t idx = (rowbase + qrow) * DMODEL + colbase + n * 16 + cl;
        Oh[idx] = f2bf(ov);
      }
}

extern "C" void kernel_launch(void* const* d_in, const int* in_sizes, int n_in,
                              void* d_out, int out_size, void* d_ws, size_t ws_size,
                              hipStream_t stream) {
  const float* x  = (const float*)d_in[0];
  const float* Wq = (const float*)d_in[1];
  const float* Wk = (const float*)d_in[2];
  const float* Wv = (const float*)d_in[3];
  const float* Wo = (const float*)d_in[4];
  float* out = (float*)d_out;

  const int M = NB * SEQ;      // 4096
  const int D = DMODEL;        // 1024
  char* ws = (char*)d_ws;
  const size_t MB = 1u << 20;
  u16* xh16 = (u16*)(ws + 0 * MB);    // 8 MB fp16
  u16* qh16 = (u16*)(ws + 8 * MB);    // 8 MB fp16
  u16* kh16 = (u16*)(ws + 16 * MB);   // 8 MB fp16
  u16* vt   = (u16*)(ws + 24 * MB);   // 8 MB bf16, transposed [1024][4096]
  u16* oh   = (u16*)(ws + 40 * MB);   // 8 MB bf16
  u16* wq16 = (u16*)(ws + 48 * MB);   // 2 MB each
  u16* wk16 = (u16*)(ws + 50 * MB);
  u16* wv16 = (u16*)(ws + 52 * MB);
  u16* wob  = (u16*)(ws + 54 * MB);

  // one fused cast launch: x,Wq,Wk,Wv -> fp16 ; Wo -> bf16
  {
    int total = M * D / 8 + 4 * (D * D / 8);
    cast_all_kernel<<<(total + 255) / 256, 256, 0, stream>>>(
        x, Wq, Wk, Wv, Wo, xh16, wq16, wk16, wv16, wob);
  }

  // fused QKV projections, fp16 1-term, double-buffered: Q,K fp16; V bf16 Vt
  {
    GemmPtrs P;
    P.B[0] = wq16; P.B[1] = wk16; P.B[2] = wv16;
    P.C0[0] = qh16; P.C0[1] = kh16; P.C0[2] = vt;
    P.mode[0] = 0; P.mode[1] = 0; P.mode[2] = 1;
    gemm_bt_kernel<true, 128><<<dim3(D / 128, M / 128, 3), 256, 0, stream>>>(
        xh16, P, nullptr, M, D, D, 0);
  }

  // RoPE on fp16 Q,K (in place)
  rope_kernel<<<(2 * M * (D / 2) + 255) / 256, 256, 0, stream>>>(qh16, kh16);

  // causal flash attention: 512 blocks of 4 waves, pair-balanced heavy-first
  attn_kernel<<<dim3(NH * NB, 8), 256, 0, stream>>>(qh16, kh16, vt, oh);

  // output projection: bf16, 128x64 tile, double-buffered, direct f32 out
  {
    GemmPtrs P;
    P.B[0] = wob; P.B[1] = wob; P.B[2] = wob;
    P.C0[0] = nullptr; P.C0[1] = nullptr; P.C0[2] = nullptr;
    P.mode[0] = 0; P.mode[1] = 0; P.mode[2] = 0;
    gemm_bt_kernel<false, 64><<<dim3(D / 64, M / 128, 1), 256, 0, stream>>>(
        oh, P, out, M, D, D, 1);
  }
}

// Round 17
// 103.388 us; speedup vs baseline: 1.1506x; 1.0469x over previous
//
#include <hip/hip_runtime.h>
#include <stdint.h>

typedef unsigned short u16;
typedef short s16x8 __attribute__((ext_vector_type(8)));
typedef __bf16 bf16x8 __attribute__((ext_vector_type(8)));
typedef _Float16 f16x8 __attribute__((ext_vector_type(8)));
typedef float f32x4 __attribute__((ext_vector_type(4)));

#define SEQ    1024
#define DMODEL 1024
#define NB     4
#define NH     16
#define DH     64
#define QBLK   128
#define KVB    64
#define LOG2E  1.4426950408889634f

// ---------- scalar conversion helpers ----------
__device__ __forceinline__ u16 f2bf(float f) {
  uint32_t u = __builtin_bit_cast(uint32_t, f);
  u += 0x7fffu + ((u >> 16) & 1u);   // round-to-nearest-even
  return (u16)(u >> 16);
}
__device__ __forceinline__ u16 f2bf_rz(float f) {   // truncate (p>=0; bias cancels in P/l)
  return (u16)(__builtin_bit_cast(uint32_t, f) >> 16);
}
__device__ __forceinline__ float bf2f(u16 h) {
  uint32_t u = ((uint32_t)h) << 16;
  return __builtin_bit_cast(float, u);
}
__device__ __forceinline__ u16 f2h(float f) {       // f32 -> fp16 RNE
  return __builtin_bit_cast(u16, (_Float16)f);
}
__device__ __forceinline__ float h2f(u16 u) {
  return (float)__builtin_bit_cast(_Float16, u);
}

#define MFMA16(a, b, c)  __builtin_amdgcn_mfma_f32_16x16x32_bf16((a), (b), (c), 0, 0, 0)
#define MFMA16H(a, b, c) __builtin_amdgcn_mfma_f32_16x16x32_f16((a), (b), (c), 0, 0, 0)

template<bool F16>
__device__ __forceinline__ f32x4 MF(s16x8 a, s16x8 b, f32x4 c) {
  if constexpr (F16)
    return MFMA16H(__builtin_bit_cast(f16x8, a), __builtin_bit_cast(f16x8, b), c);
  else
    return MFMA16(__builtin_bit_cast(bf16x8, a), __builtin_bit_cast(bf16x8, b), c);
}

// ---------- async global->LDS (16B) ----------
__device__ __forceinline__ void gload_lds16(const u16* g, uintptr_t lds_addr) {
  __builtin_amdgcn_global_load_lds(
      (__attribute__((address_space(1))) void*)(uintptr_t)g,
      (__attribute__((address_space(3))) void*)lds_addr,
      16, 0, 0);
}

// ---------------- fused cast: x,Wq,Wk,Wv -> fp16 ; Wo -> bf16 (one launch) ----------------
__global__ void cast_all_kernel(
    const float* __restrict__ x, const float* __restrict__ wq,
    const float* __restrict__ wk, const float* __restrict__ wv,
    const float* __restrict__ wo,
    u16* __restrict__ xd, u16* __restrict__ wqd, u16* __restrict__ wkd,
    u16* __restrict__ wvd, u16* __restrict__ wod)
{
  const int NX = (NB * SEQ * DMODEL) / 8;   // 524288 chunks
  const int NW = (DMODEL * DMODEL) / 8;     // 131072 chunks
  int c = blockIdx.x * blockDim.x + threadIdx.x;
  const float* src; u16* dst; bool tobf = false;
  if (c < NX)                { src = x;  dst = xd; }
  else if ((c -= NX) < NW)   { src = wq; dst = wqd; }
  else if ((c -= NW) < NW)   { src = wk; dst = wkd; }
  else if ((c -= NW) < NW)   { src = wv; dst = wvd; }
  else if ((c -= NW) < NW)   { src = wo; dst = wod; tobf = true; }
  else return;
  float f[8];
  float4 v0 = *(const float4*)(src + (size_t)c * 8);
  float4 v1 = *(const float4*)(src + (size_t)c * 8 + 4);
  f[0] = v0.x; f[1] = v0.y; f[2] = v0.z; f[3] = v0.w;
  f[4] = v1.x; f[5] = v1.y; f[6] = v1.z; f[7] = v1.w;
  union { u16 u[8]; uint4 v; } H;
#pragma unroll
  for (int e = 0; e < 8; ++e) H.u[e] = tobf ? f2bf(f[e]) : f2h(f[e]);
  *(uint4*)(dst + (size_t)c * 8) = H.v;
}

// ---------------- RoPE on fp16 Q,K (in place; standalone — epilogue fusion
// regressed twice (R10 +30us, R15 +19us), do not re-attempt) ----------------
__global__ void rope_kernel(u16* __restrict__ Q, u16* __restrict__ K) {
  const int nP = (NB * SEQ) * (DMODEL / 2);
  int idx = blockIdx.x * blockDim.x + threadIdx.x;
  u16* buf; int p;
  if (idx < nP) { buf = Q; p = idx; }
  else          { buf = K; p = idx - nP; }
  int row = p >> 9;           // 512 pairs per row
  int pi  = p & 511;
  int t   = row & (SEQ - 1);
  int fi  = pi & 31;
  float inv = exp2f((float)fi * (-13.287712379549449f / 32.0f)); // 10000^(-fi/32)
  float ang = (float)t * inv;
  float sn, cs;
  sincosf(ang, &sn, &cs);
  size_t off = (size_t)row * DMODEL + pi * 2;
  uint32_t v = *(uint32_t*)(buf + off);
  float e = h2f((u16)(v & 0xffffu));
  float o = h2f((u16)(v >> 16));
  float re = e * cs - o * sn;
  float ro = e * sn + o * cs;
  *(uint32_t*)(buf + off) = (uint32_t)f2h(re) | ((uint32_t)f2h(ro) << 16);
}

// ---------------- GEMM: C = A @ B^T, 128xBN tile, BK=64, counted-vmcnt dbuf ----------------
// R16 post-mortem: __syncthreads lowers to s_waitcnt vmcnt(0)+barrier -> it
// DRAINED the just-issued prefetch (guide T4: never vmcnt(0) in main loop).
// Fix: issue next tile's NLOADS -> s_waitcnt vmcnt(NLOADS) (waits only the
// PREVIOUS tile's loads, new ones stay in flight) -> s_barrier -> compute ->
// s_barrier (frees buf for next iter's overwrite). hasnext is block-uniform.
// F16=true: fp16 MFMA, mode-0 stores fp16. F16=false: bf16 MFMA.
// 8-slot XOR swizzle: 0 bank conflicts (R9). No XCD remap (R10), no rope fusion.
// mode 1: bf16 transposed out (Vt[col][row]). out_f32: direct f32 store.
struct GemmPtrs {
  const u16* B[3]; u16* C0[3]; int mode[3];
};

template<bool F16, int BN>
__global__ __launch_bounds__(256) void gemm_bt_kernel(
    const u16* __restrict__ A,
    GemmPtrs P, float* __restrict__ CF,
    int M, int N, int K, int out_f32)
{
  constexpr int NF = BN / 32;                   // n-frags per wave
  constexpr int BCH = BN / 32;                  // B staging chunks per thread
  __shared__ __align__(16) u16 sA[2][128 * 64];  // 2 x 16 KB
  __shared__ __align__(16) u16 sB[2][BN * 64];   // 2 x 16|8 KB
  const int t = threadIdx.x, lane = t & 63;
  const int wave = t >> 6;
  const int g = lane >> 4, cl = lane & 15;
  const int z = blockIdx.z;
  const u16* B = P.B[z];
  const int n0 = blockIdx.x * BN, m0 = blockIdx.y * 128;
  const int wr = wave >> 1, wc = wave & 1;

  // staging offsets for a [R][64] u16 tile: chunk c -> row c>>3, slot c&7,
  // source col pre-swizzled (rule #21), read-side applies same XOR involution
  int srow[4], scol[4], soff[4];
#pragma unroll
  for (int j = 0; j < 4; ++j) {
    int c = j * 256 + t;
    srow[j] = c >> 3;
    scol[j] = ((c & 7) ^ (srow[j] & 7)) * 8;
    soff[j] = c * 16;
  }

  f32x4 acc[4][NF] = {};

  // prologue: stage k0=0 into buffer 0 (NLOADS = 4 + BCH per thread)
#pragma unroll
  for (int j = 0; j < 4; ++j)
    gload_lds16(A + (size_t)(m0 + srow[j]) * K + scol[j], (uintptr_t)&sA[0][0] + soff[j]);
#pragma unroll
  for (int j = 0; j < BCH; ++j)
    gload_lds16(B + (size_t)(n0 + srow[j]) * K + scol[j], (uintptr_t)&sB[0][0] + soff[j]);

  int cur = 0;
  for (int k0 = 0; k0 < K; k0 += 64) {
    const bool hasnext = (k0 + 64 < K);   // block-uniform
    if (hasnext) {
      const int nk = k0 + 64;
#pragma unroll
      for (int j = 0; j < 4; ++j)
        gload_lds16(A + (size_t)(m0 + srow[j]) * K + nk + scol[j],
                    (uintptr_t)&sA[cur ^ 1][0] + soff[j]);
#pragma unroll
      for (int j = 0; j < BCH; ++j)
        gload_lds16(B + (size_t)(n0 + srow[j]) * K + nk + scol[j],
                    (uintptr_t)&sB[cur ^ 1][0] + soff[j]);
      // wait for PREVIOUS tile's loads only; the NLOADS just issued stay in flight
      if constexpr (BN == 128) asm volatile("s_waitcnt vmcnt(8)" ::: "memory");
      else                     asm volatile("s_waitcnt vmcnt(6)" ::: "memory");
    } else {
      asm volatile("s_waitcnt vmcnt(0)" ::: "memory");
    }
    __builtin_amdgcn_s_barrier();   // everyone's current-tile loads landed

    s16x8 af[4][2];
#pragma unroll
    for (int m = 0; m < 4; ++m) {
      int row = wr * 64 + m * 16 + cl;
#pragma unroll
      for (int kk = 0; kk < 2; ++kk)
        af[m][kk] = *(const s16x8*)&sA[cur][row * 64 + (((kk * 4 + g) ^ (row & 7)) * 8)];
    }
#pragma unroll
    for (int n = 0; n < NF; ++n) {
      int row = wc * (BN / 2) + n * 16 + cl;
      s16x8 b0 = *(const s16x8*)&sB[cur][row * 64 + ((g ^ (row & 7)) * 8)];
      s16x8 b1 = *(const s16x8*)&sB[cur][row * 64 + (((4 + g) ^ (row & 7)) * 8)];
#pragma unroll
      for (int m = 0; m < 4; ++m) {
        acc[m][n] = MF<F16>(af[m][0], b0, acc[m][n]);
        acc[m][n] = MF<F16>(af[m][1], b1, acc[m][n]);
      }
    }
    __builtin_amdgcn_s_barrier();   // all waves done reading buf[cur]
    cur ^= 1;
  }

  // epilogue: C/D layout col=lane&15, row=(lane>>4)*4+reg  [m89]
  if (out_f32) {
#pragma unroll
    for (int m = 0; m < 4; ++m)
#pragma unroll
      for (int n = 0; n < NF; ++n)
#pragma unroll
        for (int r = 0; r < 4; ++r) {
          int row = m0 + wr * 64 + m * 16 + g * 4 + r;
          int col = n0 + wc * (BN / 2) + n * 16 + cl;
          CF[(size_t)row * N + col] = acc[m][n][r];
        }
  } else if (P.mode[z] == 1) {
    u16* VT = P.C0[z];
#pragma unroll
    for (int m = 0; m < 4; ++m)
#pragma unroll
      for (int n = 0; n < NF; ++n) {
        int row0 = m0 + wr * 64 + m * 16 + g * 4;
        int col = n0 + wc * (BN / 2) + n * 16 + cl;
        union { u16 u[4]; uint2 v; } pk;
#pragma unroll
        for (int r = 0; r < 4; ++r) pk.u[r] = f2bf(acc[m][n][r]);
        *(uint2*)&VT[(size_t)col * M + row0] = pk.v;
      }
  } else {
    u16* C = P.C0[z];
#pragma unroll
    for (int m = 0; m < 4; ++m)
#pragma unroll
      for (int n = 0; n < NF; ++n)
#pragma unroll
        for (int r = 0; r < 4; ++r) {
          int row = m0 + wr * 64 + m * 16 + g * 4 + r;
          int col = n0 + wc * (BN / 2) + n * 16 + cl;
          float v = acc[m][n][r];
          C[(size_t)row * N + col] = F16 ? f2h(v) : f2bf(v);
        }
  }
}

// ---------------- flash attention: fp16 QK^T, bf16 PV, no-max, 2-phase ----------------
// Q,K fp16 (1-term; 8x finer mantissa than bf16). P stays bf16 (exp(s) up to
// e^50 would overflow fp16); V bf16. LDS 50 KB. (R13-validated, absmax 0.017.)
__global__ __launch_bounds__(256, 2) void attn_kernel(
    const u16* __restrict__ Q, const u16* __restrict__ K,
    const u16* __restrict__ Vt,
    u16* __restrict__ Oh)
{
  __shared__ __align__(16) u16 sK [2][KVB * 64];   // fp16 [buf][key][d]  16KB
  __shared__ __align__(16) u16 sVt[2][DH * KVB];   // bf16 [buf][d][key]  16KB
  __shared__ __align__(16) u16 sP[128 * 72];       // bf16, 18KB, wave-private rows

  const int t = threadIdx.x, lane = t & 63, wave = t >> 6;
  const int g = lane >> 4, cl = lane & 15;
  const int h = blockIdx.x & (NH - 1), b = blockIdx.x >> 4;
  const int y = blockIdx.y;
  const int qi = (y < 4) ? (7 - y) : (y - 4);  // paired work balance + heavy-first
  const int q0 = qi * QBLK;
  const size_t rowbase = (size_t)b * SEQ;
  const int colbase = h * DH;
  const int MT = NB * SEQ;

  const u16* Kb  = K + rowbase * DMODEL + colbase;
  const u16* Vtb = Vt + (size_t)(h * DH) * MT + b * SEQ;

  int srow[2], scol[2], soff[2];
#pragma unroll
  for (int j = 0; j < 2; ++j) {
    int c = j * 256 + t;
    srow[j] = c >> 3;
    scol[j] = ((c & 7) ^ (srow[j] & 7)) * 8;
    soff[j] = c * 16;
  }

  // loop-invariant LDS read offsets
  int koff0[4], koff1[4];
#pragma unroll
  for (int n = 0; n < 4; ++n) {
    int row = n * 16 + cl;
    koff0[n] = row * 64 + ((g ^ (row & 7)) * 8);
    koff1[n] = row * 64 + (((4 + g) ^ (row & 7)) * 8);
  }
  int paoff[2][2];
#pragma unroll
  for (int kk = 0; kk < 2; ++kk) {
    paoff[kk][0] = (wave * 32 + cl) * 72 + kk * 32 + g * 8;
    paoff[kk][1] = (wave * 32 + 16 + cl) * 72 + kk * 32 + g * 8;
  }

  // Q fragments fp16 (A-op: lane holds A[row=cl][k=g*8+e], second mfma k+32)
  f16x8 qf[2][2];
#pragma unroll
  for (int mf = 0; mf < 2; ++mf) {
    int qrow = q0 + wave * 32 + mf * 16 + cl;
    const u16* pq = Q + (rowbase + qrow) * DMODEL + colbase + g * 8;
    qf[mf][0] = __builtin_bit_cast(f16x8, *(const s16x8*)pq);
    qf[mf][1] = __builtin_bit_cast(f16x8, *(const s16x8*)(pq + 32));
  }

  bf16x8 ones;
#pragma unroll
  for (int e = 0; e < 8; ++e) ones[e] = (__bf16)1.0f;

  f32x4 o_acc[2][4] = {};
  f32x4 o_l[2] = {};

  const int last = 2 * qi + 1;
  const int wrow0 = q0 + wave * 32;
  const int prow0 = wave * 32;

  // prologue: stage tile 0 into buffer 0
#pragma unroll
  for (int j = 0; j < 2; ++j) {
    gload_lds16(Kb + (size_t)srow[j] * DMODEL + scol[j],  (uintptr_t)&sK[0][0] + soff[j]);
    gload_lds16(Vtb + (size_t)srow[j] * MT + scol[j],     (uintptr_t)&sVt[0][0] + soff[j]);
  }
  __syncthreads();

  int cur = 0;
  for (int kt = 0; kt <= last; ++kt) {
    const int kv0 = kt * KVB;
    // issue next tile's staging FIRST (hidden under this tile's compute)
    if (kt < last) {
      const int nk = kv0 + KVB;
#pragma unroll
      for (int j = 0; j < 2; ++j) {
        gload_lds16(Kb + (size_t)(nk + srow[j]) * DMODEL + scol[j],
                    (uintptr_t)&sK[cur ^ 1][0] + soff[j]);
        gload_lds16(Vtb + (size_t)srow[j] * MT + nk + scol[j],
                    (uintptr_t)&sVt[cur ^ 1][0] + soff[j]);
      }
    }

    const bool skip = (wrow0 + 31) < kv0;   // wave fully masked (diag tiles)
    if (!skip) {
      const bool needmask = (kv0 + 63) > wrow0;

      // QK^T: fp16 single-term
      f32x4 s[2][4];
      __builtin_amdgcn_s_setprio(1);
#pragma unroll
      for (int n = 0; n < 4; ++n) {
        f16x8 k0 = __builtin_bit_cast(f16x8, *(const s16x8*)&sK[cur][koff0[n]]);
        f16x8 k1 = __builtin_bit_cast(f16x8, *(const s16x8*)&sK[cur][koff1[n]]);
#pragma unroll
        for (int mf = 0; mf < 2; ++mf) {
          f32x4 zz = {};
          zz = MFMA16H(qf[mf][0], k0, zz);
          zz = MFMA16H(qf[mf][1], k1, zz);
          s[mf][n] = zz;
        }
      }
      __builtin_amdgcn_s_setprio(0);

      // no-max softmax: p = exp2(s*log2e), zeroed past the diagonal
#pragma unroll
      for (int mf = 0; mf < 2; ++mf) {
#pragma unroll
        for (int r = 0; r < 4; ++r) {
          int qg = wrow0 + mf * 16 + g * 4 + r;
          int prow = prow0 + mf * 16 + g * 4 + r;
#pragma unroll
          for (int n = 0; n < 4; ++n) {
            float p = exp2f(s[mf][n][r] * LOG2E);
            if (needmask && (kv0 + n * 16 + cl > qg)) p = 0.0f;
            sP[prow * 72 + n * 16 + cl] = f2bf_rz(p);
          }
        }
      }

      // PV: O += P(32x64)*Vt ; l += P*1 (bf16 MFMA)
      __builtin_amdgcn_s_setprio(1);
#pragma unroll
      for (int kk = 0; kk < 2; ++kk) {
        bf16x8 pa0 = *(const bf16x8*)&sP[paoff[kk][0]];
        bf16x8 pa1 = *(const bf16x8*)&sP[paoff[kk][1]];
#pragma unroll
        for (int n = 0; n < 4; ++n) {
          bf16x8 vf = *(const bf16x8*)&sVt[cur][(kk == 0) ? koff0[n] : koff1[n]];
          o_acc[0][n] = MFMA16(pa0, vf, o_acc[0][n]);
          o_acc[1][n] = MFMA16(pa1, vf, o_acc[1][n]);
        }
        o_l[0] = MFMA16(pa0, ones, o_l[0]);
        o_l[1] = MFMA16(pa1, ones, o_l[1]);
      }
      __builtin_amdgcn_s_setprio(0);
    }

    __syncthreads();   // drains vmcnt(0): prefetch landed; frees buf cur
    cur ^= 1;
  }

  // epilogue: normalize by l, store bf16 (feeds bf16 Wo GEMM)
#pragma unroll
  for (int mf = 0; mf < 2; ++mf)
#pragma unroll
    for (int n = 0; n < 4; ++n)
#pragma unroll
      for (int r = 0; r < 4; ++r) {
        float ov = o_acc[mf][n][r] / o_l[mf][r];
        int qrow = q0 + wave * 32 + mf * 16 + g * 4 + r;
        size_t idx = (rowbase + qrow) * DMODEL + colbase + n * 16 + cl;
        Oh[idx] = f2bf(ov);
      }
}

extern "C" void kernel_launch(void* const* d_in, const int* in_sizes, int n_in,
                              void* d_out, int out_size, void* d_ws, size_t ws_size,
                              hipStream_t stream) {
  const float* x  = (const float*)d_in[0];
  const float* Wq = (const float*)d_in[1];
  const float* Wk = (const float*)d_in[2];
  const float* Wv = (const float*)d_in[3];
  const float* Wo = (const float*)d_in[4];
  float* out = (float*)d_out;

  const int M = NB * SEQ;      // 4096
  const int D = DMODEL;        // 1024
  char* ws = (char*)d_ws;
  const size_t MB = 1u << 20;
  u16* xh16 = (u16*)(ws + 0 * MB);    // 8 MB fp16
  u16* qh16 = (u16*)(ws + 8 * MB);    // 8 MB fp16
  u16* kh16 = (u16*)(ws + 16 * MB);   // 8 MB fp16
  u16* vt   = (u16*)(ws + 24 * MB);   // 8 MB bf16, transposed [1024][4096]
  u16* oh   = (u16*)(ws + 40 * MB);   // 8 MB bf16
  u16* wq16 = (u16*)(ws + 48 * MB);   // 2 MB each
  u16* wk16 = (u16*)(ws + 50 * MB);
  u16* wv16 = (u16*)(ws + 52 * MB);
  u16* wob  = (u16*)(ws + 54 * MB);

  // one fused cast launch: x,Wq,Wk,Wv -> fp16 ; Wo -> bf16
  {
    int total = M * D / 8 + 4 * (D * D / 8);
    cast_all_kernel<<<(total + 255) / 256, 256, 0, stream>>>(
        x, Wq, Wk, Wv, Wo, xh16, wq16, wk16, wv16, wob);
  }

  // fused QKV projections, fp16 1-term, counted-vmcnt dbuf: Q,K fp16; V bf16 Vt
  {
    GemmPtrs P;
    P.B[0] = wq16; P.B[1] = wk16; P.B[2] = wv16;
    P.C0[0] = qh16; P.C0[1] = kh16; P.C0[2] = vt;
    P.mode[0] = 0; P.mode[1] = 0; P.mode[2] = 1;
    gemm_bt_kernel<true, 128><<<dim3(D / 128, M / 128, 3), 256, 0, stream>>>(
        xh16, P, nullptr, M, D, D, 0);
  }

  // RoPE on fp16 Q,K (in place)
  rope_kernel<<<(2 * M * (D / 2) + 255) / 256, 256, 0, stream>>>(qh16, kh16);

  // causal flash attention: 512 blocks of 4 waves, pair-balanced heavy-first
  attn_kernel<<<dim3(NH * NB, 8), 256, 0, stream>>>(qh16, kh16, vt, oh);

  // output projection: bf16, 128x64 tile, counted-vmcnt dbuf, direct f32 out
  {
    GemmPtrs P;
    P.B[0] = wob; P.B[1] = wob; P.B[2] = wob;
    P.C0[0] = nullptr; P.C0[1] = nullptr; P.C0[2] = nullptr;
    P.mode[0] = 0; P.mode[1] = 0; P.mode[2] = 0;
    gemm_bt_kernel<false, 64><<<dim3(D / 64, M / 128, 1), 256, 0, stream>>>(
        oh, P, out, M, D, D, 1);
  }
}

// Round 18
// 99.610 us; speedup vs baseline: 1.1942x; 1.0379x over previous
//
#include <hip/hip_runtime.h>
#include <stdint.h>

typedef unsigned short u16;
typedef short s16x8 __attribute__((ext_vector_type(8)));
typedef __bf16 bf16x8 __attribute__((ext_vector_type(8)));
typedef _Float16 f16x8 __attribute__((ext_vector_type(8)));
typedef float f32x4 __attribute__((ext_vector_type(4)));

#define SEQ    1024
#define DMODEL 1024
#define NB     4
#define NH     16
#define DH     64
#define QBLK   128
#define KVB    64
#define LOG2E  1.4426950408889634f
#define ROPE_C (-13.287712379549449f / 32.0f)   // log2(10000)/(-32)

// ---------- scalar conversion helpers ----------
__device__ __forceinline__ u16 f2bf(float f) {
  uint32_t u = __builtin_bit_cast(uint32_t, f);
  u += 0x7fffu + ((u >> 16) & 1u);   // round-to-nearest-even
  return (u16)(u >> 16);
}
__device__ __forceinline__ u16 f2bf_rz(float f) {   // truncate (p>=0; bias cancels in P/l)
  return (u16)(__builtin_bit_cast(uint32_t, f) >> 16);
}
__device__ __forceinline__ float bf2f(u16 h) {
  uint32_t u = ((uint32_t)h) << 16;
  return __builtin_bit_cast(float, u);
}
__device__ __forceinline__ u16 f2h(float f) {       // f32 -> fp16 RNE
  return __builtin_bit_cast(u16, (_Float16)f);
}
__device__ __forceinline__ float h2f(u16 u) {
  return (float)__builtin_bit_cast(_Float16, u);
}

#define MFMA16(a, b, c)  __builtin_amdgcn_mfma_f32_16x16x32_bf16((a), (b), (c), 0, 0, 0)
#define MFMA16H(a, b, c) __builtin_amdgcn_mfma_f32_16x16x32_f16((a), (b), (c), 0, 0, 0)

template<bool F16>
__device__ __forceinline__ f32x4 MF(s16x8 a, s16x8 b, f32x4 c) {
  if constexpr (F16)
    return MFMA16H(__builtin_bit_cast(f16x8, a), __builtin_bit_cast(f16x8, b), c);
  else
    return MFMA16(__builtin_bit_cast(bf16x8, a), __builtin_bit_cast(bf16x8, b), c);
}

// ---------- async global->LDS (16B) ----------
__device__ __forceinline__ void gload_lds16(const u16* g, uintptr_t lds_addr) {
  __builtin_amdgcn_global_load_lds(
      (__attribute__((address_space(1))) void*)(uintptr_t)g,
      (__attribute__((address_space(3))) void*)lds_addr,
      16, 0, 0);
}

// ---------------- fused cast: x,Wq,Wk,Wv -> fp16 ; Wo -> bf16 (one launch) ----------------
__global__ void cast_all_kernel(
    const float* __restrict__ x, const float* __restrict__ wq,
    const float* __restrict__ wk, const float* __restrict__ wv,
    const float* __restrict__ wo,
    u16* __restrict__ xd, u16* __restrict__ wqd, u16* __restrict__ wkd,
    u16* __restrict__ wvd, u16* __restrict__ wod)
{
  const int NX = (NB * SEQ * DMODEL) / 8;   // 524288 chunks
  const int NW = (DMODEL * DMODEL) / 8;     // 131072 chunks
  int c = blockIdx.x * blockDim.x + threadIdx.x;
  const float* src; u16* dst; bool tobf = false;
  if (c < NX)                { src = x;  dst = xd; }
  else if ((c -= NX) < NW)   { src = wq; dst = wqd; }
  else if ((c -= NW) < NW)   { src = wk; dst = wkd; }
  else if ((c -= NW) < NW)   { src = wv; dst = wvd; }
  else if ((c -= NW) < NW)   { src = wo; dst = wod; tobf = true; }
  else return;
  float f[8];
  float4 v0 = *(const float4*)(src + (size_t)c * 8);
  float4 v1 = *(const float4*)(src + (size_t)c * 8 + 4);
  f[0] = v0.x; f[1] = v0.y; f[2] = v0.z; f[3] = v0.w;
  f[4] = v1.x; f[5] = v1.y; f[6] = v1.z; f[7] = v1.w;
  union { u16 u[8]; uint4 v; } H;
#pragma unroll
  for (int e = 0; e < 8; ++e) H.u[e] = tobf ? f2bf(f[e]) : f2h(f[e]);
  *(uint4*)(dst + (size_t)c * 8) = H.v;
}

// ---------------- RoPE on fp16 K only (Q is rotated in-register in attn) ----------------
__global__ void rope_k_kernel(u16* __restrict__ K) {
  int p = blockIdx.x * blockDim.x + threadIdx.x;   // M * D/2 pairs
  int row = p >> 9;           // 512 pairs per row
  int pi  = p & 511;
  int t   = row & (SEQ - 1);
  int fi  = pi & 31;
  float inv = exp2f((float)fi * ROPE_C);   // 10000^(-fi/32)
  float ang = (float)t * inv;
  float sn, cs;
  sincosf(ang, &sn, &cs);
  size_t off = (size_t)row * DMODEL + pi * 2;
  uint32_t v = *(uint32_t*)(K + off);
  float e = h2f((u16)(v & 0xffffu));
  float o = h2f((u16)(v >> 16));
  float re = e * cs - o * sn;
  float ro = e * sn + o * cs;
  *(uint32_t*)(K + off) = (uint32_t)f2h(re) | ((uint32_t)f2h(ro) << 16);
}

// ---------------- QKV projection, shared-A pair blocks ----------------
// z=0 (pair): stage A + Bq + Bk per K-step (48 KB), 64 MFMA/wave into two acc
// banks -> intensity 87 FLOP/staged-byte (R12-parity; fp16 1-term alone was 64).
// z=1 (V): stage A + Bv (32 KB), 32 MFMA/wave, bf16-transposed Vt epilogue.
// One launch: 512 mixed blocks keep the machine filled. Serial-drain loop
// (R12's proven 40%-MfmaUtil structure). launch_bounds(256,2): VGPR<=256, no spill.
__global__ __launch_bounds__(256, 2) void qkv_kernel(
    const u16* __restrict__ A, const u16* __restrict__ Bq,
    const u16* __restrict__ Bk, const u16* __restrict__ Bv,
    u16* __restrict__ Cq, u16* __restrict__ Ck, u16* __restrict__ VT,
    int M, int N, int K)
{
  __shared__ __align__(16) u16 sA [128 * 64];   // 16 KB
  __shared__ __align__(16) u16 sB0[128 * 64];   // 16 KB
  __shared__ __align__(16) u16 sB1[128 * 64];   // 16 KB (pair blocks only)
  const int t = threadIdx.x, lane = t & 63;
  const int wave = t >> 6;
  const int g = lane >> 4, cl = lane & 15;
  const bool pair = (blockIdx.z == 0);
  const int n0 = blockIdx.x * 128, m0 = blockIdx.y * 128;
  const int wr = wave >> 1, wc = wave & 1;

  int srow[4], scol[4], soff[4];
#pragma unroll
  for (int j = 0; j < 4; ++j) {
    int c = j * 256 + t;
    srow[j] = c >> 3;
    scol[j] = ((c & 7) ^ (srow[j] & 7)) * 8;
    soff[j] = c * 16;
  }

  f32x4 acc0[4][4] = {};
  f32x4 acc1[4][4] = {};

  for (int k0 = 0; k0 < K; k0 += 64) {
#pragma unroll
    for (int j = 0; j < 4; ++j)
      gload_lds16(A + (size_t)(m0 + srow[j]) * K + k0 + scol[j], (uintptr_t)sA + soff[j]);
    if (pair) {
#pragma unroll
      for (int j = 0; j < 4; ++j) {
        gload_lds16(Bq + (size_t)(n0 + srow[j]) * K + k0 + scol[j], (uintptr_t)sB0 + soff[j]);
        gload_lds16(Bk + (size_t)(n0 + srow[j]) * K + k0 + scol[j], (uintptr_t)sB1 + soff[j]);
      }
    } else {
#pragma unroll
      for (int j = 0; j < 4; ++j)
        gload_lds16(Bv + (size_t)(n0 + srow[j]) * K + k0 + scol[j], (uintptr_t)sB0 + soff[j]);
    }
    __syncthreads();   // drains vmcnt(0): staging landed

    s16x8 af[4][2];
#pragma unroll
    for (int m = 0; m < 4; ++m) {
      int row = wr * 64 + m * 16 + cl;
#pragma unroll
      for (int kk = 0; kk < 2; ++kk)
        af[m][kk] = *(const s16x8*)&sA[row * 64 + (((kk * 4 + g) ^ (row & 7)) * 8)];
    }
#pragma unroll
    for (int n = 0; n < 4; ++n) {
      int row = wc * 64 + n * 16 + cl;
      int o0 = row * 64 + ((g ^ (row & 7)) * 8);
      int o1 = row * 64 + (((4 + g) ^ (row & 7)) * 8);
      s16x8 b0 = *(const s16x8*)&sB0[o0];
      s16x8 b1 = *(const s16x8*)&sB0[o1];
#pragma unroll
      for (int m = 0; m < 4; ++m) {
        acc0[m][n] = MF<true>(af[m][0], b0, acc0[m][n]);
        acc0[m][n] = MF<true>(af[m][1], b1, acc0[m][n]);
      }
      if (pair) {
        s16x8 c0 = *(const s16x8*)&sB1[o0];
        s16x8 c1 = *(const s16x8*)&sB1[o1];
#pragma unroll
        for (int m = 0; m < 4; ++m) {
          acc1[m][n] = MF<true>(af[m][0], c0, acc1[m][n]);
          acc1[m][n] = MF<true>(af[m][1], c1, acc1[m][n]);
        }
      }
    }
    __syncthreads();
  }

  // epilogue: C/D layout col=lane&15, row=(lane>>4)*4+reg  [m89]
  if (pair) {
#pragma unroll
    for (int m = 0; m < 4; ++m)
#pragma unroll
      for (int n = 0; n < 4; ++n)
#pragma unroll
        for (int r = 0; r < 4; ++r) {
          int row = m0 + wr * 64 + m * 16 + g * 4 + r;
          int col = n0 + wc * 64 + n * 16 + cl;
          Cq[(size_t)row * N + col] = f2h(acc0[m][n][r]);
          Ck[(size_t)row * N + col] = f2h(acc1[m][n][r]);
        }
  } else {
#pragma unroll
    for (int m = 0; m < 4; ++m)
#pragma unroll
      for (int n = 0; n < 4; ++n) {
        int row0 = m0 + wr * 64 + m * 16 + g * 4;
        int col = n0 + wc * 64 + n * 16 + cl;
        union { u16 u[4]; uint2 v; } pk;
#pragma unroll
        for (int r = 0; r < 4; ++r) pk.u[r] = f2bf(acc0[m][n][r]);
        *(uint2*)&VT[(size_t)col * M + row0] = pk.v;
      }
  }
}

// ---------------- Wo GEMM: 128x64 tile, counted-vmcnt dbuf (R17-validated) ----------------
__global__ __launch_bounds__(256) void gemm_wo_kernel(
    const u16* __restrict__ A, const u16* __restrict__ B,
    float* __restrict__ CF, int M, int N, int K)
{
  constexpr int BN = 64;
  __shared__ __align__(16) u16 sA[2][128 * 64];  // 2 x 16 KB
  __shared__ __align__(16) u16 sB[2][BN * 64];   // 2 x 8 KB
  const int t = threadIdx.x, lane = t & 63;
  const int wave = t >> 6;
  const int g = lane >> 4, cl = lane & 15;
  const int n0 = blockIdx.x * BN, m0 = blockIdx.y * 128;
  const int wr = wave >> 1, wc = wave & 1;

  int srow[4], scol[4], soff[4];
#pragma unroll
  for (int j = 0; j < 4; ++j) {
    int c = j * 256 + t;
    srow[j] = c >> 3;
    scol[j] = ((c & 7) ^ (srow[j] & 7)) * 8;
    soff[j] = c * 16;
  }

  f32x4 acc[4][2] = {};

  // prologue: stage k0=0 into buffer 0 (6 loads/thread)
#pragma unroll
  for (int j = 0; j < 4; ++j)
    gload_lds16(A + (size_t)(m0 + srow[j]) * K + scol[j], (uintptr_t)&sA[0][0] + soff[j]);
#pragma unroll
  for (int j = 0; j < 2; ++j)
    gload_lds16(B + (size_t)(n0 + srow[j]) * K + scol[j], (uintptr_t)&sB[0][0] + soff[j]);

  int cur = 0;
  for (int k0 = 0; k0 < K; k0 += 64) {
    const bool hasnext = (k0 + 64 < K);   // block-uniform
    if (hasnext) {
      const int nk = k0 + 64;
#pragma unroll
      for (int j = 0; j < 4; ++j)
        gload_lds16(A + (size_t)(m0 + srow[j]) * K + nk + scol[j],
                    (uintptr_t)&sA[cur ^ 1][0] + soff[j]);
#pragma unroll
      for (int j = 0; j < 2; ++j)
        gload_lds16(B + (size_t)(n0 + srow[j]) * K + nk + scol[j],
                    (uintptr_t)&sB[cur ^ 1][0] + soff[j]);
      asm volatile("s_waitcnt vmcnt(6)" ::: "memory");  // prev tile only
    } else {
      asm volatile("s_waitcnt vmcnt(0)" ::: "memory");
    }
    __builtin_amdgcn_s_barrier();

    s16x8 af[4][2];
#pragma unroll
    for (int m = 0; m < 4; ++m) {
      int row = wr * 64 + m * 16 + cl;
#pragma unroll
      for (int kk = 0; kk < 2; ++kk)
        af[m][kk] = *(const s16x8*)&sA[cur][row * 64 + (((kk * 4 + g) ^ (row & 7)) * 8)];
    }
#pragma unroll
    for (int n = 0; n < 2; ++n) {
      int row = wc * 32 + n * 16 + cl;
      s16x8 b0 = *(const s16x8*)&sB[cur][row * 64 + ((g ^ (row & 7)) * 8)];
      s16x8 b1 = *(const s16x8*)&sB[cur][row * 64 + (((4 + g) ^ (row & 7)) * 8)];
#pragma unroll
      for (int m = 0; m < 4; ++m) {
        acc[m][n] = MF<false>(af[m][0], b0, acc[m][n]);
        acc[m][n] = MF<false>(af[m][1], b1, acc[m][n]);
      }
    }
    __builtin_amdgcn_s_barrier();
    cur ^= 1;
  }

#pragma unroll
  for (int m = 0; m < 4; ++m)
#pragma unroll
    for (int n = 0; n < 2; ++n)
#pragma unroll
      for (int r = 0; r < 4; ++r) {
        int row = m0 + wr * 64 + m * 16 + g * 4 + r;
        int col = n0 + wc * 32 + n * 16 + cl;
        CF[(size_t)row * N + col] = acc[m][n][r];
      }
}

// ---------------- flash attention: fp16 QK^T (Q RoPE'd in-register), bf16 PV ----------------
// Q loaded unrotated; pairs are register-adjacent (d = g*8+e), rotated in f32
// at fragment load (16 sincosf/thread, once) -> one less fp16 rounding vs the
// old pre-rotated-q path. K pre-rotated by rope_k_kernel. No-max softmax.
__global__ __launch_bounds__(256, 2) void attn_kernel(
    const u16* __restrict__ Q, const u16* __restrict__ K,
    const u16* __restrict__ Vt,
    u16* __restrict__ Oh)
{
  __shared__ __align__(16) u16 sK [2][KVB * 64];   // fp16 [buf][key][d]  16KB
  __shared__ __align__(16) u16 sVt[2][DH * KVB];   // bf16 [buf][d][key]  16KB
  __shared__ __align__(16) u16 sP[128 * 72];       // bf16, 18KB, wave-private rows

  const int t = threadIdx.x, lane = t & 63, wave = t >> 6;
  const int g = lane >> 4, cl = lane & 15;
  const int h = blockIdx.x & (NH - 1), b = blockIdx.x >> 4;
  const int y = blockIdx.y;
  const int qi = (y < 4) ? (7 - y) : (y - 4);  // paired work balance + heavy-first
  const int q0 = qi * QBLK;
  const size_t rowbase = (size_t)b * SEQ;
  const int colbase = h * DH;
  const int MT = NB * SEQ;

  const u16* Kb  = K + rowbase * DMODEL + colbase;
  const u16* Vtb = Vt + (size_t)(h * DH) * MT + b * SEQ;

  int srow[2], scol[2], soff[2];
#pragma unroll
  for (int j = 0; j < 2; ++j) {
    int c = j * 256 + t;
    srow[j] = c >> 3;
    scol[j] = ((c & 7) ^ (srow[j] & 7)) * 8;
    soff[j] = c * 16;
  }

  // loop-invariant LDS read offsets
  int koff0[4], koff1[4];
#pragma unroll
  for (int n = 0; n < 4; ++n) {
    int row = n * 16 + cl;
    koff0[n] = row * 64 + ((g ^ (row & 7)) * 8);
    koff1[n] = row * 64 + (((4 + g) ^ (row & 7)) * 8);
  }
  int paoff[2][2];
#pragma unroll
  for (int kk = 0; kk < 2; ++kk) {
    paoff[kk][0] = (wave * 32 + cl) * 72 + kk * 32 + g * 8;
    paoff[kk][1] = (wave * 32 + 16 + cl) * 72 + kk * 32 + g * 8;
  }

  // Q fragments fp16 with in-register RoPE (pairs are adjacent elems 2j,2j+1)
  f16x8 qf[2][2];
#pragma unroll
  for (int mf = 0; mf < 2; ++mf) {
    int qrow = q0 + wave * 32 + mf * 16 + cl;
    const u16* pq = Q + (rowbase + qrow) * DMODEL + colbase + g * 8;
    s16x8 raw0 = *(const s16x8*)pq;
    s16x8 raw1 = *(const s16x8*)(pq + 32);
    f16x8 r0, r1;
#pragma unroll
    for (int j = 0; j < 4; ++j) {
      float sn, cs;
      // frag0: head-local d = g*8 + 2j -> fi = 4g + j
      sincosf((float)qrow * exp2f((float)(4 * g + j) * ROPE_C), &sn, &cs);
      float e = h2f((u16)raw0[2 * j]), o = h2f((u16)raw0[2 * j + 1]);
      r0[2 * j]     = (_Float16)(e * cs - o * sn);
      r0[2 * j + 1] = (_Float16)(e * sn + o * cs);
      // frag1: d = 32 + g*8 + 2j -> fi = 16 + 4g + j
      sincosf((float)qrow * exp2f((float)(16 + 4 * g + j) * ROPE_C), &sn, &cs);
      e = h2f((u16)raw1[2 * j]); o = h2f((u16)raw1[2 * j + 1]);
      r1[2 * j]     = (_Float16)(e * cs - o * sn);
      r1[2 * j + 1] = (_Float16)(e * sn + o * cs);
    }
    qf[mf][0] = r0; qf[mf][1] = r1;
  }

  bf16x8 ones;
#pragma unroll
  for (int e = 0; e < 8; ++e) ones[e] = (__bf16)1.0f;

  f32x4 o_acc[2][4] = {};
  f32x4 o_l[2] = {};

  const int last = 2 * qi + 1;
  const int wrow0 = q0 + wave * 32;
  const int prow0 = wave * 32;

  // prologue: stage tile 0 into buffer 0
#pragma unroll
  for (int j = 0; j < 2; ++j) {
    gload_lds16(Kb + (size_t)srow[j] * DMODEL + scol[j],  (uintptr_t)&sK[0][0] + soff[j]);
    gload_lds16(Vtb + (size_t)srow[j] * MT + scol[j],     (uintptr_t)&sVt[0][0] + soff[j]);
  }
  __syncthreads();

  int cur = 0;
  for (int kt = 0; kt <= last; ++kt) {
    const int kv0 = kt * KVB;
    // issue next tile's staging FIRST (hidden under this tile's compute)
    if (kt < last) {
      const int nk = kv0 + KVB;
#pragma unroll
      for (int j = 0; j < 2; ++j) {
        gload_lds16(Kb + (size_t)(nk + srow[j]) * DMODEL + scol[j],
                    (uintptr_t)&sK[cur ^ 1][0] + soff[j]);
        gload_lds16(Vtb + (size_t)srow[j] * MT + nk + scol[j],
                    (uintptr_t)&sVt[cur ^ 1][0] + soff[j]);
      }
    }

    const bool skip = (wrow0 + 31) < kv0;   // wave fully masked (diag tiles)
    if (!skip) {
      const bool needmask = (kv0 + 63) > wrow0;

      // QK^T: fp16 single-term
      f32x4 s[2][4];
      __builtin_amdgcn_s_setprio(1);
#pragma unroll
      for (int n = 0; n < 4; ++n) {
        f16x8 k0 = __builtin_bit_cast(f16x8, *(const s16x8*)&sK[cur][koff0[n]]);
        f16x8 k1 = __builtin_bit_cast(f16x8, *(const s16x8*)&sK[cur][koff1[n]]);
#pragma unroll
        for (int mf = 0; mf < 2; ++mf) {
          f32x4 zz = {};
          zz = MFMA16H(qf[mf][0], k0, zz);
          zz = MFMA16H(qf[mf][1], k1, zz);
          s[mf][n] = zz;
        }
      }
      __builtin_amdgcn_s_setprio(0);

      // no-max softmax: p = exp2(s*log2e), zeroed past the diagonal
#pragma unroll
      for (int mf = 0; mf < 2; ++mf) {
#pragma unroll
        for (int r = 0; r < 4; ++r) {
          int qg = wrow0 + mf * 16 + g * 4 + r;
          int prow = prow0 + mf * 16 + g * 4 + r;
#pragma unroll
          for (int n = 0; n < 4; ++n) {
            float p = exp2f(s[mf][n][r] * LOG2E);
            if (needmask && (kv0 + n * 16 + cl > qg)) p = 0.0f;
            sP[prow * 72 + n * 16 + cl] = f2bf_rz(p);
          }
        }
      }

      // PV: O += P(32x64)*Vt ; l += P*1 (bf16 MFMA)
      __builtin_amdgcn_s_setprio(1);
#pragma unroll
      for (int kk = 0; kk < 2; ++kk) {
        bf16x8 pa0 = *(const bf16x8*)&sP[paoff[kk][0]];
        bf16x8 pa1 = *(const bf16x8*)&sP[paoff[kk][1]];
#pragma unroll
        for (int n = 0; n < 4; ++n) {
          bf16x8 vf = *(const bf16x8*)&sVt[cur][(kk == 0) ? koff0[n] : koff1[n]];
          o_acc[0][n] = MFMA16(pa0, vf, o_acc[0][n]);
          o_acc[1][n] = MFMA16(pa1, vf, o_acc[1][n]);
        }
        o_l[0] = MFMA16(pa0, ones, o_l[0]);
        o_l[1] = MFMA16(pa1, ones, o_l[1]);
      }
      __builtin_amdgcn_s_setprio(0);
    }

    __syncthreads();   // drains vmcnt(0): prefetch landed; frees buf cur
    cur ^= 1;
  }

  // epilogue: normalize by l, store bf16 (feeds bf16 Wo GEMM)
#pragma unroll
  for (int mf = 0; mf < 2; ++mf)
#pragma unroll
    for (int n = 0; n < 4; ++n)
#pragma unroll
      for (int r = 0; r < 4; ++r) {
        float ov = o_acc[mf][n][r] / o_l[mf][r];
        int qrow = q0 + wave * 32 + mf * 16 + g * 4 + r;
        size_t idx = (rowbase + qrow) * DMODEL + colbase + n * 16 + cl;
        Oh[idx] = f2bf(ov);
      }
}

extern "C" void kernel_launch(void* const* d_in, const int* in_sizes, int n_in,
                              void* d_out, int out_size, void* d_ws, size_t ws_size,
                              hipStream_t stream) {
  const float* x  = (const float*)d_in[0];
  const float* Wq = (const float*)d_in[1];
  const float* Wk = (const float*)d_in[2];
  const float* Wv = (const float*)d_in[3];
  const float* Wo = (const float*)d_in[4];
  float* out = (float*)d_out;

  const int M = NB * SEQ;      // 4096
  const int D = DMODEL;        // 1024
  char* ws = (char*)d_ws;
  const size_t MB = 1u << 20;
  u16* xh16 = (u16*)(ws + 0 * MB);    // 8 MB fp16
  u16* qh16 = (u16*)(ws + 8 * MB);    // 8 MB fp16 (unrotated; attn rotates Q)
  u16* kh16 = (u16*)(ws + 16 * MB);   // 8 MB fp16 (rotated in place)
  u16* vt   = (u16*)(ws + 24 * MB);   // 8 MB bf16, transposed [1024][4096]
  u16* oh   = (u16*)(ws + 40 * MB);   // 8 MB bf16
  u16* wq16 = (u16*)(ws + 48 * MB);   // 2 MB each
  u16* wk16 = (u16*)(ws + 50 * MB);
  u16* wv16 = (u16*)(ws + 52 * MB);
  u16* wob  = (u16*)(ws + 54 * MB);

  // one fused cast launch: x,Wq,Wk,Wv -> fp16 ; Wo -> bf16
  {
    int total = M * D / 8 + 4 * (D * D / 8);
    cast_all_kernel<<<(total + 255) / 256, 256, 0, stream>>>(
        x, Wq, Wk, Wv, Wo, xh16, wq16, wk16, wv16, wob);
  }

  // QKV: z=0 fused Q+K shared-A pair blocks; z=1 V (Vt out). 512 blocks.
  qkv_kernel<<<dim3(D / 128, M / 128, 2), 256, 0, stream>>>(
      xh16, wq16, wk16, wv16, qh16, kh16, vt, M, D, D);

  // RoPE on K only (Q rotated in attn)
  rope_k_kernel<<<(M * (D / 2)) / 256, 256, 0, stream>>>(kh16);

  // causal flash attention: 512 blocks of 4 waves, pair-balanced heavy-first
  attn_kernel<<<dim3(NH * NB, 8), 256, 0, stream>>>(qh16, kh16, vt, oh);

  // output projection: bf16, 128x64 tile, counted-vmcnt dbuf, direct f32 out
  gemm_wo_kernel<<<dim3(D / 64, M / 128, 1), 256, 0, stream>>>(
      oh, wob, out, M, D, D);
}